// Round 1
// baseline (1695.230 us; speedup 1.0000x reference)
//
#include <hip/hip_runtime.h>
#include <hip/hip_bf16.h>

#define S_LEN   1024
#define D_MODEL 768
#define N_HEAD  12
#define D_HEAD  64
#define BATCH   4
#define T_LEN   2047      // 2*S-1
#define INF_VAL 1000000.0f
#define SCALE   0.125f    // 1/sqrt(64)
#define LN_EPSF 1e-9f

// ---------------------------------------------------------------------------
// detect whether token_type_mat was pushed as int32 (1) or int8/bool (0)
// ---------------------------------------------------------------------------
__global__ void detect_kernel(const unsigned char* __restrict__ p, int* __restrict__ flag)
{
    if (threadIdx.x == 0 && blockIdx.x == 0) {
        int nz = 0;
        for (int k = 0; k < 4096; k += 4)
            nz += (p[k+1] != 0) + (p[k+2] != 0) + (p[k+3] != 0);
        *flag = (nz == 0) ? 1 : 0;   // all-hi-bytes-zero => int32 little-endian 0/1
    }
}

// ---------------------------------------------------------------------------
// C[M,N] = A[M,K] @ B[K,N] * scale (+ bias)   (row-major, N%64==0, K%16==0)
// ---------------------------------------------------------------------------
__global__ __launch_bounds__(256)
void gemm_kernel(const float* __restrict__ A, const float* __restrict__ B,
                 const float* __restrict__ bias, float* __restrict__ C,
                 int M, int N, int K, float scale, int has_bias)
{
    __shared__ float As[16][65];
    __shared__ float Bs[16][64];
    int tid = threadIdx.x;
    int tx = tid & 15, ty = tid >> 4;
    int m0 = blockIdx.y * 64, n0 = blockIdx.x * 64;
    float acc[4][4] = {};

    for (int k0 = 0; k0 < K; k0 += 16) {
        {   // A tile -> As[k][m] (transposed)
            int r  = tid >> 2;
            int cg = (tid & 3) * 4;
            float4 v = make_float4(0.f, 0.f, 0.f, 0.f);
            if (m0 + r < M) v = *(const float4*)(A + (size_t)(m0 + r) * K + k0 + cg);
            As[cg+0][r] = v.x; As[cg+1][r] = v.y; As[cg+2][r] = v.z; As[cg+3][r] = v.w;
        }
        {   // B tile -> Bs[k][n]
            int r  = tid >> 4;
            int cg = (tid & 15) * 4;
            float4 v = *(const float4*)(B + (size_t)(k0 + r) * N + n0 + cg);
            *(float4*)&Bs[r][cg] = v;
        }
        __syncthreads();
        #pragma unroll
        for (int kk = 0; kk < 16; ++kk) {
            float a0 = As[kk][ty], a1 = As[kk][ty+16], a2 = As[kk][ty+32], a3 = As[kk][ty+48];
            float b0 = Bs[kk][tx], b1 = Bs[kk][tx+16], b2 = Bs[kk][tx+32], b3 = Bs[kk][tx+48];
            acc[0][0] += a0*b0; acc[0][1] += a0*b1; acc[0][2] += a0*b2; acc[0][3] += a0*b3;
            acc[1][0] += a1*b0; acc[1][1] += a1*b1; acc[1][2] += a1*b2; acc[1][3] += a1*b3;
            acc[2][0] += a2*b0; acc[2][1] += a2*b1; acc[2][2] += a2*b2; acc[2][3] += a2*b3;
            acc[3][0] += a3*b0; acc[3][1] += a3*b1; acc[3][2] += a3*b2; acc[3][3] += a3*b3;
        }
        __syncthreads();
    }
    #pragma unroll
    for (int i = 0; i < 4; ++i) {
        int row = m0 + ty + i*16;
        if (row >= M) continue;
        #pragma unroll
        for (int j = 0; j < 4; ++j) {
            int col = n0 + tx + j*16;
            float v = acc[i][j] * scale;
            if (has_bias) v += bias[col];
            C[(size_t)row * N + col] = v;
        }
    }
}

// ---------------------------------------------------------------------------
// tt[(b*S+i)*NH*2 + n*2 + s2] = sum_h (qh + r_s_bias*scale) * seg_embed[s2,n,h]
// ---------------------------------------------------------------------------
__global__ __launch_bounds__(256)
void ttbias_kernel(const float* __restrict__ qh, const float* __restrict__ rsb,
                   const float* __restrict__ seg, float* __restrict__ tt)
{
    int idx = blockIdx.x * 256 + threadIdx.x;
    if (idx >= BATCH * S_LEN * N_HEAD * 2) return;
    int s2  = idx & 1;
    int n   = (idx >> 1) % N_HEAD;
    int row = idx / (2 * N_HEAD);         // b*S + i
    const float* q  = qh  + (size_t)row * D_MODEL + n * D_HEAD;
    const float* sg = seg + ((size_t)s2 * N_HEAD + n) * D_HEAD;
    const float* rb = rsb + n * D_HEAD;
    float s = 0.f;
    for (int h = 0; h < D_HEAD; ++h) s += (q[h] + rb[h] * SCALE) * sg[h];
    tt[idx] = s;
}

// ---------------------------------------------------------------------------
// fused attention: per (b, head, 32 q-rows) online-softmax over 16 j-tiles
// ---------------------------------------------------------------------------
__global__ __launch_bounds__(256)
void attn_kernel(const float* __restrict__ qh, const float* __restrict__ kh,
                 const float* __restrict__ vh, const float* __restrict__ rhd,
                 const float* __restrict__ tt, const float* __restrict__ cls,
                 const void* __restrict__ ttm, const int* __restrict__ amask,
                 const float* __restrict__ rwb, const float* __restrict__ rrb,
                 const int* __restrict__ flag, float* __restrict__ av)
{
    __shared__ float qw[32][65];   // q + r_w_bias*scale
    __shared__ float qr[32][65];   // q + r_r_bias*scale
    __shared__ float kt[64][64];
    __shared__ float vt[64][64];
    __shared__ float sc[32][65];   // p values
    __shared__ float rh[96][65];   // r_head window
    __shared__ float cl_s[32][65]; // cls tile
    __shared__ float ts_s[32][65]; // cls*tt_sel - INF*(1-mask)
    __shared__ float pm[8][32];
    __shared__ float ps[8][32];

    int tid = threadIdx.x;
    int i0 = blockIdx.x * 32;
    int n  = blockIdx.y;
    int b  = blockIdx.z;
    int is_i32 = *flag;

    // stage q block, add per-head biases
    for (int rep = 0; rep < 2; ++rep) {
        int idx = rep * 256 + tid;          // 512 float4s = 32 rows x 16
        int r  = idx >> 4;
        int c4 = (idx & 15) * 4;
        float4 v = *(const float4*)(qh + ((size_t)(b * S_LEN + i0 + r)) * D_MODEL + n * D_HEAD + c4);
        const float* wb = rwb + n * D_HEAD + c4;
        const float* rb = rrb + n * D_HEAD + c4;
        qw[r][c4+0] = v.x + wb[0]*SCALE; qw[r][c4+1] = v.y + wb[1]*SCALE;
        qw[r][c4+2] = v.z + wb[2]*SCALE; qw[r][c4+3] = v.w + wb[3]*SCALE;
        qr[r][c4+0] = v.x + rb[0]*SCALE; qr[r][c4+1] = v.y + rb[1]*SCALE;
        qr[r][c4+2] = v.z + rb[2]*SCALE; qr[r][c4+3] = v.w + rb[3]*SCALE;
    }

    int i = tid & 31;
    int g = tid >> 5;    // score: j-group; PV: d-group
    float m_run = -1e30f, l_run = 0.f;
    float acc[8] = {0.f,0.f,0.f,0.f,0.f,0.f,0.f,0.f};

    for (int jt = 0; jt < 16; ++jt) {
        int j0 = jt * 64;
        __syncthreads();
        // ---- stage K,V tiles ----
        for (int rep = 0; rep < 4; ++rep) {
            int idx = rep * 256 + tid;       // 1024 float4s
            int r  = idx >> 4;
            int c4 = (idx & 15) * 4;
            size_t base = ((size_t)(b * S_LEN + j0 + r)) * D_MODEL + n * D_HEAD + c4;
            *(float4*)&kt[r][c4] = *(const float4*)(kh + base);
            *(float4*)&vt[r][c4] = *(const float4*)(vh + base);
        }
        // ---- stage r_head window: rows t = w0..w0+95, window row = jl - ii + 31 ----
        int w0 = 1024 + j0 - i0 - 31;
        for (int rep = 0; rep < 6; ++rep) {
            int idx = rep * 256 + tid;       // 1536 float4s
            int r  = idx >> 4;
            int c4 = (idx & 15) * 4;
            int t  = w0 + r;
            float4 v = make_float4(0.f, 0.f, 0.f, 0.f);
            if (t >= 0 && t < T_LEN)
                v = *(const float4*)(rhd + (size_t)t * D_MODEL + n * D_HEAD + c4);
            rh[r][c4+0] = v.x; rh[r][c4+1] = v.y; rh[r][c4+2] = v.z; rh[r][c4+3] = v.w;
        }
        // ---- stage cls + (cls * token-type select - mask) tiles ----
        for (int rep = 0; rep < 8; ++rep) {
            int idx = rep * 256 + tid;       // 2048 scalars
            int r = idx >> 6, c = idx & 63;
            int gi = i0 + r, gj = j0 + c;
            float cv = cls[(size_t)gi * S_LEN + gj];
            int tm;
            size_t toff = ((size_t)(b * S_LEN + gi)) * S_LEN + gj;
            if (is_i32) tm = ((const int*)ttm)[toff];
            else        tm = ((const unsigned char*)ttm)[toff];
            float ttv = tt[(((size_t)(b * S_LEN + gi)) * N_HEAD + n) * 2 + (tm ? 1 : 0)];
            float am = (float)amask[b * S_LEN + gj];
            cl_s[r][c] = cv;
            ts_s[r][c] = cv * ttv - INF_VAL * (1.f - am);
        }
        __syncthreads();

        // ---- scores: 8 per thread (row i, cols g*8..g*8+7) ----
        float cs[8]  = {0.f,0.f,0.f,0.f,0.f,0.f,0.f,0.f};
        float pos[8] = {0.f,0.f,0.f,0.f,0.f,0.f,0.f,0.f};
        int rb0 = g * 8 - i + 31;            // window row base
        for (int h = 0; h < D_HEAD; ++h) {
            float qwv = qw[i][h], qrv = qr[i][h];
            #pragma unroll
            for (int q = 0; q < 8; ++q) {
                cs[q]  += qwv * kt[g*8 + q][h];
                pos[q] += qrv * rh[rb0 + q][h];
            }
        }
        // edge fixup: out[0,1023] uses qr[row 1] . r_head[0]
        if (i0 == 0 && j0 == 960 && tid == 224) {   // i==0, g==7 -> jl==63
            float p = 0.f;
            for (int h = 0; h < D_HEAD; ++h)
                p += qr[1][h] * rhd[(size_t)n * D_HEAD + h];
            pos[7] = p;
        }
        float lmax = -1e30f;
        float svals[8];
        #pragma unroll
        for (int q = 0; q < 8; ++q) {
            int jl = g * 8 + q;
            float s = cs[q] + cl_s[i][jl] * pos[q] + ts_s[i][jl];
            svals[q] = s;
            lmax = fmaxf(lmax, s);
        }
        pm[g][i] = lmax;
        __syncthreads();

        float mt = pm[0][i];
        #pragma unroll
        for (int k = 1; k < 8; ++k) mt = fmaxf(mt, pm[k][i]);
        float m_new = fmaxf(m_run, mt);
        float alpha = __expf(m_run - m_new);
        float psum = 0.f;
        #pragma unroll
        for (int q = 0; q < 8; ++q) {
            float p = __expf(svals[q] - m_new);
            sc[i][g*8 + q] = p;
            psum += p;
        }
        ps[g][i] = psum;
        __syncthreads();

        float add = 0.f;
        #pragma unroll
        for (int k = 0; k < 8; ++k) add += ps[k][i];
        l_run = alpha * l_run + add;
        m_run = m_new;

        #pragma unroll
        for (int c = 0; c < 8; ++c) {
            float a = acc[c] * alpha;
            int d = g * 8 + c;
            for (int j = 0; j < 64; ++j) a += sc[i][j] * vt[j][d];
            acc[c] = a;
        }
    }

    float inv = 1.f / l_run;
    size_t ob = ((size_t)(b * S_LEN + i0 + i)) * D_MODEL + n * D_HEAD + g * 8;
    #pragma unroll
    for (int c = 0; c < 8; ++c) av[ob + c] = acc[c] * inv;
}

// ---------------------------------------------------------------------------
// LayerNorm(query + attn_out) * g + b
// ---------------------------------------------------------------------------
__global__ __launch_bounds__(256)
void ln_kernel(const float* __restrict__ query, const float* __restrict__ ao,
               const float* __restrict__ gam, const float* __restrict__ bet,
               float* __restrict__ out)
{
    int row = blockIdx.x;
    int tid = threadIdx.x;
    size_t base = (size_t)row * D_MODEL;
    float xv[3];
    float s = 0.f, sq = 0.f;
    #pragma unroll
    for (int k = 0; k < 3; ++k) {
        int c = tid + k * 256;
        float v = query[base + c] + ao[base + c];
        xv[k] = v; s += v; sq += v * v;
    }
    for (int off = 32; off > 0; off >>= 1) {
        s  += __shfl_down(s, off);
        sq += __shfl_down(sq, off);
    }
    __shared__ float rs[4], rq[4];
    __shared__ float mean_s, inv_s;
    int wid = tid >> 6, lane = tid & 63;
    if (lane == 0) { rs[wid] = s; rq[wid] = sq; }
    __syncthreads();
    if (tid == 0) {
        float S0 = rs[0] + rs[1] + rs[2] + rs[3];
        float Q0 = rq[0] + rq[1] + rq[2] + rq[3];
        float mean = S0 / (float)D_MODEL;
        float var  = Q0 / (float)D_MODEL - mean * mean;
        mean_s = mean;
        inv_s  = rsqrtf(var + LN_EPSF);
    }
    __syncthreads();
    float mean = mean_s, inv = inv_s;
    #pragma unroll
    for (int k = 0; k < 3; ++k) {
        int c = tid + k * 256;
        out[base + c] = (xv[k] - mean) * inv * gam[c] + bet[c];
    }
}

// ---------------------------------------------------------------------------
extern "C" void kernel_launch(void* const* d_in, const int* in_sizes, int n_in,
                              void* d_out, int out_size, void* d_ws, size_t ws_size,
                              hipStream_t stream)
{
    const float* query = (const float*)d_in[0];
    const float* key   = (const float*)d_in[1];
    const float* value = (const float*)d_in[2];
    const float* r     = (const float*)d_in[3];
    const void*  ttm   = d_in[4];
    const int*   amask = (const int*)d_in[5];
    const float* cls   = (const float*)d_in[6];
    const float* Wq    = (const float*)d_in[7];
    const float* Wk    = (const float*)d_in[8];
    const float* bk    = (const float*)d_in[9];
    const float* Wv    = (const float*)d_in[10];
    const float* bv    = (const float*)d_in[11];
    const float* Wpost = (const float*)d_in[12];
    const float* bpost = (const float*)d_in[13];
    const float* ln_g  = (const float*)d_in[14];
    const float* ln_b  = (const float*)d_in[15];
    const float* rwb   = (const float*)d_in[16];
    const float* rrb   = (const float*)d_in[17];
    const float* rker  = (const float*)d_in[18];
    const float* rsb   = (const float*)d_in[19];
    const float* seg   = (const float*)d_in[20];

    float* ws  = (float*)d_ws;
    float* qh  = ws;                 // 4096*768
    float* kh  = ws + 3145728;       // 4096*768
    float* vh  = ws + 6291456;       // 4096*768
    float* rhd = ws + 9437184;       // 2047*768
    float* tt  = ws + 11009280;      // 4*1024*12*2
    float* av  = ws + 11107584;      // 4096*768
    float* ao  = kh;                 // reuse (K no longer needed post-attention)
    int*   flag = (int*)(ws + 14253312);

    detect_kernel<<<1, 64, 0, stream>>>((const unsigned char*)ttm, flag);

    dim3 gproj(12, 64);
    gemm_kernel<<<gproj, 256, 0, stream>>>(query, Wq, nullptr, qh, 4096, 768, 768, SCALE, 0);
    gemm_kernel<<<gproj, 256, 0, stream>>>(key,   Wk, bk,      kh, 4096, 768, 768, 1.f, 1);
    gemm_kernel<<<gproj, 256, 0, stream>>>(value, Wv, bv,      vh, 4096, 768, 768, 1.f, 1);
    dim3 grh(12, 32);
    gemm_kernel<<<grh, 256, 0, stream>>>(r, rker, nullptr, rhd, 2047, 768, 768, 1.f, 0);

    ttbias_kernel<<<384, 256, 0, stream>>>(qh, rsb, seg, tt);

    dim3 gattn(32, 12, 4);
    attn_kernel<<<gattn, 256, 0, stream>>>(qh, kh, vh, rhd, tt, cls, ttm, amask,
                                           rwb, rrb, flag, av);

    gemm_kernel<<<gproj, 256, 0, stream>>>(av, Wpost, bpost, ao, 4096, 768, 768, 1.f, 1);

    ln_kernel<<<4096, 256, 0, stream>>>(query, ao, ln_g, ln_b, (float*)d_out);
}

// Round 3
// 665.953 us; speedup vs baseline: 2.5456x; 2.5456x over previous
//
#include <hip/hip_runtime.h>
#include <hip/hip_bf16.h>

#define S_LEN   1024
#define D_MODEL 768
#define N_HEAD  12
#define D_HEAD  64
#define BATCH   4
#define T_LEN   2047      // 2*S-1
#define INF_VAL 1000000.0f
#define SCALE   0.125f    // 1/sqrt(64)
#define LN_EPSF 1e-9f

typedef __attribute__((ext_vector_type(8))) __bf16 bf8;
typedef __attribute__((ext_vector_type(4))) __bf16 bf4;
typedef __attribute__((ext_vector_type(4))) float  f32x4;

// ---------------------------------------------------------------------------
// detect whether token_type_mat was pushed as int32 (1) or int8/bool (0)
// ---------------------------------------------------------------------------
__global__ void detect_kernel(const unsigned char* __restrict__ p, int* __restrict__ flag)
{
    if (threadIdx.x == 0 && blockIdx.x == 0) {
        int nz = 0;
        for (int k = 0; k < 4096; k += 4)
            nz += (p[k+1] != 0) + (p[k+2] != 0) + (p[k+3] != 0);
        *flag = (nz == 0) ? 1 : 0;
    }
}

// ---------------------------------------------------------------------------
// C[M,N] = A[M,K] @ B[K,N] * scale (+ bias); out fp32 or bf16
// ---------------------------------------------------------------------------
__global__ __launch_bounds__(256)
void gemm_kernel(const float* __restrict__ A, const float* __restrict__ B,
                 const float* __restrict__ bias, void* __restrict__ C,
                 int M, int N, int K, float scale, int has_bias, int out_bf16)
{
    __shared__ float As[16][65];
    __shared__ float Bs[16][64];
    int tid = threadIdx.x;
    int tx = tid & 15, ty = tid >> 4;
    int m0 = blockIdx.y * 64, n0 = blockIdx.x * 64;
    float acc[4][4] = {};

    for (int k0 = 0; k0 < K; k0 += 16) {
        {
            int r  = tid >> 2;
            int cg = (tid & 3) * 4;
            float4 v = make_float4(0.f, 0.f, 0.f, 0.f);
            if (m0 + r < M) v = *(const float4*)(A + (size_t)(m0 + r) * K + k0 + cg);
            As[cg+0][r] = v.x; As[cg+1][r] = v.y; As[cg+2][r] = v.z; As[cg+3][r] = v.w;
        }
        {
            int r  = tid >> 4;
            int cg = (tid & 15) * 4;
            float4 v = *(const float4*)(B + (size_t)(k0 + r) * N + n0 + cg);
            *(float4*)&Bs[r][cg] = v;
        }
        __syncthreads();
        #pragma unroll
        for (int kk = 0; kk < 16; ++kk) {
            float a0 = As[kk][ty], a1 = As[kk][ty+16], a2 = As[kk][ty+32], a3 = As[kk][ty+48];
            float b0 = Bs[kk][tx], b1 = Bs[kk][tx+16], b2 = Bs[kk][tx+32], b3 = Bs[kk][tx+48];
            acc[0][0] += a0*b0; acc[0][1] += a0*b1; acc[0][2] += a0*b2; acc[0][3] += a0*b3;
            acc[1][0] += a1*b0; acc[1][1] += a1*b1; acc[1][2] += a1*b2; acc[1][3] += a1*b3;
            acc[2][0] += a2*b0; acc[2][1] += a2*b1; acc[2][2] += a2*b2; acc[2][3] += a2*b3;
            acc[3][0] += a3*b0; acc[3][1] += a3*b1; acc[3][2] += a3*b2; acc[3][3] += a3*b3;
        }
        __syncthreads();
    }
    #pragma unroll
    for (int i = 0; i < 4; ++i) {
        int row = m0 + ty + i*16;
        if (row >= M) continue;
        #pragma unroll
        for (int j = 0; j < 4; ++j) {
            int col = n0 + tx + j*16;
            float v = acc[i][j] * scale;
            if (has_bias) v += bias[col];
            if (out_bf16) ((__bf16*)C)[(size_t)row * N + col] = (__bf16)v;
            else          ((float*)C)[(size_t)row * N + col] = v;
        }
    }
}

// ---------------------------------------------------------------------------
// tt[(b*S+i)*NH*2 + n*2 + s2] = sum_h (qh + r_s_bias*scale) * seg_embed
// ---------------------------------------------------------------------------
__global__ __launch_bounds__(256)
void ttbias_kernel(const __bf16* __restrict__ qh, const float* __restrict__ rsb,
                   const float* __restrict__ seg, float* __restrict__ tt)
{
    int idx = blockIdx.x * 256 + threadIdx.x;
    if (idx >= BATCH * S_LEN * N_HEAD * 2) return;
    int s2  = idx & 1;
    int n   = (idx >> 1) % N_HEAD;
    int row = idx / (2 * N_HEAD);
    const __bf16* q  = qh  + (size_t)row * D_MODEL + n * D_HEAD;
    const float* sg = seg + ((size_t)s2 * N_HEAD + n) * D_HEAD;
    const float* rb = rsb + n * D_HEAD;
    float s = 0.f;
    for (int h = 0; h < D_HEAD; ++h) s += ((float)q[h] + rb[h] * SCALE) * sg[h];
    tt[idx] = s;
}

// ---------------------------------------------------------------------------
// MFMA fused attention. grid (16, 12, 4), 256 thr. 64 q-rows/block, 16/wave.
// ---------------------------------------------------------------------------
__device__ __forceinline__ int swz_addr(int row, int byte_in_row) {
    return ((row << 7) + byte_in_row) ^ ((row & 7) << 4);
}

__global__ __launch_bounds__(256)
void attn_kernel(const __bf16* __restrict__ qh, const __bf16* __restrict__ kh,
                 const __bf16* __restrict__ vh, const __bf16* __restrict__ rhd,
                 const float* __restrict__ tt, const float* __restrict__ cls,
                 const void* __restrict__ ttm, const int* __restrict__ amask,
                 const float* __restrict__ rwb, const float* __restrict__ rrb,
                 const int* __restrict__ flag, float* __restrict__ av)
{
    // all tiles with 128B row stride are XOR-swizzled: byte ^= (row&7)<<4
    __shared__ __align__(16) __bf16 Kt[64*64];       // [j][h]
    __shared__ __align__(16) __bf16 Vt[64*64];       // [d][j]  (transposed)
    __shared__ __align__(16) __bf16 Rw[128*64];      // [r][h]
    __shared__ __align__(16) __bf16 Ps[4*16*64];     // per-wave P [il][jl]
    __shared__ __align__(16) __bf16 poss[4*16*84];   // per-wave pos band, stride 84
    __shared__ __align__(16) __bf16 clss[64*68];     // stride 68
    __shared__ __align__(16) __bf16 tss[64*68];      // stride 68

    int tid = threadIdx.x;
    int i0 = blockIdx.x * 64;
    int n  = blockIdx.y;
    int b  = blockIdx.z;
    int bS = b * S_LEN;
    int n64 = n * D_HEAD;
    int is_i32 = *flag;

    int lane = tid & 63, w = tid >> 6;
    int grp = lane >> 4, lcol = lane & 15;

    // ---- Q fragments (A-layout: row lcol, k = kk*32 + grp*8 .. +7) ----
    bf8 qwA[2], qrA[2];
    {
        size_t qrow = (size_t)(bS + i0 + w*16 + lcol) * D_MODEL + n64;
        #pragma unroll
        for (int kk = 0; kk < 2; ++kk) {
            int kb = kk*32 + grp*8;
            bf8 qv = *(const bf8*)(qh + qrow + kb);
            const float* wbp = rwb + n64 + kb;
            const float* rbp = rrb + n64 + kb;
            #pragma unroll
            for (int q = 0; q < 8; ++q) {
                float f = (float)qv[q];
                qwA[kk][q] = (__bf16)(f + wbp[q] * SCALE);
                qrA[kk][q] = (__bf16)(f + rbp[q] * SCALE);
            }
        }
    }

    // ---- relative-shift edge fixup value: qr_row1 . r_head[0] ----
    float fixv = 0.f;
    if (i0 == 0) {
        float qv = (float)qh[((size_t)(bS + 1)) * D_MODEL + n64 + lane] + rrb[n64 + lane] * SCALE;
        float rv = (float)rhd[n64 + lane];
        float t = qv * rv;
        #pragma unroll
        for (int m = 32; m; m >>= 1) t += __shfl_xor(t, m, 64);
        fixv = t;
    }
    bool fix = (i0 == 0 && w == 0 && lane == 15);

    float m_run[4] = {-1e30f, -1e30f, -1e30f, -1e30f};
    float l_run[4] = {0.f, 0.f, 0.f, 0.f};
    f32x4 acc[4] = {};
    const f32x4 zero4 = {0.f, 0.f, 0.f, 0.f};

    for (int jt = 0; jt < 16; ++jt) {
        int j0 = jt * 64;
        __syncthreads();

        // ---- stage K tile (bf16 copy, swizzled) ----
        #pragma unroll
        for (int rep = 0; rep < 2; ++rep) {
            int idx = rep*256 + tid;          // 512 chunks of 8
            int row = idx >> 3;
            int c8  = (idx & 7) * 8;
            bf8 v = *(const bf8*)(kh + (size_t)(bS + j0 + row) * D_MODEL + n64 + c8);
            *(bf8*)((char*)Kt + swz_addr(row, c8*2)) = v;
        }
        // ---- stage V transposed ----
        #pragma unroll
        for (int rep = 0; rep < 2; ++rep) {
            int idx = rep*256 + tid;
            int row = idx >> 3;               // j
            int c8  = (idx & 7) * 8;          // d base
            bf8 v = *(const bf8*)(vh + (size_t)(bS + j0 + row) * D_MODEL + n64 + c8);
            #pragma unroll
            for (int q = 0; q < 8; ++q) {
                int d = c8 + q;
                *((__bf16*)((char*)Vt + swz_addr(d, row*2))) = v[q];
            }
        }
        // ---- stage r_head window: t = w0 + r, r in [0,128) ----
        int w0 = j0 - i0 + 961;
        #pragma unroll
        for (int rep = 0; rep < 4; ++rep) {
            int idx = rep*256 + tid;          // 1024 chunks of 8
            int row = idx >> 3;
            int c8  = (idx & 7) * 8;
            int t = w0 + row;
            bf8 v = {};
            if (t >= 0 && t < T_LEN)
                v = *(const bf8*)(rhd + (size_t)t * D_MODEL + n64 + c8);
            *(bf8*)((char*)Rw + swz_addr(row, c8*2)) = v;
        }
        // ---- stage cls + ts tiles ----
        #pragma unroll
        for (int rep = 0; rep < 4; ++rep) {
            int idx = rep*256 + tid;          // 1024 chunks of 4
            int row = idx >> 4;
            int c4  = (idx & 15) * 4;
            int gi = i0 + row, gj = j0 + c4;
            float4 cv = *(const float4*)(cls + (size_t)gi * S_LEN + gj);
            const float* ttrow = tt + (((size_t)(bS + gi)) * N_HEAD + n) * 2;
            float t0 = ttrow[0], t1 = ttrow[1];
            float cc[4] = {cv.x, cv.y, cv.z, cv.w};
            bf4 cw, tw;
            #pragma unroll
            for (int q = 0; q < 4; ++q) {
                size_t toff = ((size_t)(bS + gi)) * S_LEN + gj + q;
                int tm = is_i32 ? ((const int*)ttm)[toff]
                                : (int)((const unsigned char*)ttm)[toff];
                float am = (float)amask[b * S_LEN + gj + q];
                cw[q] = (__bf16)cc[q];
                tw[q] = (__bf16)(cc[q] * (tm ? t1 : t0) - INF_VAL * (1.f - am));
            }
            int base = row * 68 + c4;
            *(bf4*)&clss[base] = cw;
            *(bf4*)&tss[base]  = tw;
        }
        __syncthreads();

        // ---- content scores: 4 col-tiles ----
        f32x4 sc_[4] = {zero4, zero4, zero4, zero4};
        #pragma unroll
        for (int c = 0; c < 4; ++c) {
            #pragma unroll
            for (int kk = 0; kk < 2; ++kk) {
                bf8 kb = *(const bf8*)((const char*)Kt + swz_addr(c*16 + lcol, kk*64 + grp*16));
                sc_[c] = __builtin_amdgcn_mfma_f32_16x16x32_bf16(qwA[kk], kb, sc_[c], 0, 0, 0);
            }
        }
        // ---- positional: 5 window tiles (band for this wave) ----
        int a0 = 3 - w;
        f32x4 pacc[5] = {zero4, zero4, zero4, zero4, zero4};
        #pragma unroll
        for (int pa = 0; pa < 5; ++pa) {
            int ar = (a0 + pa) * 16 + lcol;
            #pragma unroll
            for (int kk = 0; kk < 2; ++kk) {
                bf8 rb = *(const bf8*)((const char*)Rw + swz_addr(ar, kk*64 + grp*16));
                pacc[pa] = __builtin_amdgcn_mfma_f32_16x16x32_bf16(qrA[kk], rb, pacc[pa], 0, 0, 0);
            }
        }
        // write pos band to per-wave LDS (stride 84)
        __bf16* pw = poss + w * 16 * 84;
        #pragma unroll
        for (int pa = 0; pa < 5; ++pa) {
            #pragma unroll
            for (int reg = 0; reg < 4; ++reg)
                pw[(grp*4 + reg) * 84 + pa*16 + lcol] = (__bf16)pacc[pa][reg];
        }
        asm volatile("s_waitcnt lgkmcnt(0)" ::: "memory");
        __builtin_amdgcn_sched_barrier(0);

        // ---- assemble scores: s = content + cls*pos + ts ----
        float sv[4][4];
        #pragma unroll
        for (int c = 0; c < 4; ++c) {
            int jl = c*16 + lcol;
            #pragma unroll
            for (int reg = 0; reg < 4; ++reg) {
                int il = grp*4 + reg;             // wave-local row
                int rr = jl - il + 15;            // local window col
                float pv = (float)pw[il * 84 + rr];
                if (fix && jt == 15 && c == 3 && reg == 0) pv = fixv;
                int rb2 = (w*16 + il) * 68 + jl;
                float clv = (float)clss[rb2];
                float tsv = (float)tss[rb2];
                sv[c][reg] = sc_[c][reg] + clv * pv + tsv;
            }
        }

        // ---- online softmax (rows = grp*4+reg, reduce across 16 lanes) ----
        float mx[4], alpha[4], rs[4];
        #pragma unroll
        for (int reg = 0; reg < 4; ++reg)
            mx[reg] = fmaxf(fmaxf(sv[0][reg], sv[1][reg]), fmaxf(sv[2][reg], sv[3][reg]));
        #pragma unroll
        for (int msk = 1; msk < 16; msk <<= 1) {
            #pragma unroll
            for (int reg = 0; reg < 4; ++reg)
                mx[reg] = fmaxf(mx[reg], __shfl_xor(mx[reg], msk, 64));
        }
        #pragma unroll
        for (int reg = 0; reg < 4; ++reg) {
            float mn = fmaxf(m_run[reg], mx[reg]);
            alpha[reg] = __expf(m_run[reg] - mn);
            m_run[reg] = mn;
            rs[reg] = 0.f;
        }
        __bf16* psw = Ps;  // per-wave region at byte offset w*2048
        #pragma unroll
        for (int c = 0; c < 4; ++c) {
            int jl = c*16 + lcol;
            #pragma unroll
            for (int reg = 0; reg < 4; ++reg) {
                int il = grp*4 + reg;
                float p = __expf(sv[c][reg] - m_run[reg]);
                rs[reg] += p;
                *((__bf16*)((char*)psw + w*2048 + swz_addr(il, jl*2))) = (__bf16)p;
            }
        }
        #pragma unroll
        for (int msk = 1; msk < 16; msk <<= 1) {
            #pragma unroll
            for (int reg = 0; reg < 4; ++reg)
                rs[reg] += __shfl_xor(rs[reg], msk, 64);
        }
        #pragma unroll
        for (int reg = 0; reg < 4; ++reg)
            l_run[reg] = l_run[reg] * alpha[reg] + rs[reg];
        // rescale accumulators
        #pragma unroll
        for (int c = 0; c < 4; ++c) {
            #pragma unroll
            for (int reg = 0; reg < 4; ++reg) acc[c][reg] *= alpha[reg];
        }
        asm volatile("s_waitcnt lgkmcnt(0)" ::: "memory");
        __builtin_amdgcn_sched_barrier(0);

        // ---- PV: P A-frags from LDS, V^T B-frags ----
        bf8 pA[2];
        #pragma unroll
        for (int kk = 0; kk < 2; ++kk)
            pA[kk] = *(const bf8*)((const char*)psw + w*2048 + swz_addr(lcol, kk*64 + grp*16));
        #pragma unroll
        for (int c = 0; c < 4; ++c) {
            #pragma unroll
            for (int kk = 0; kk < 2; ++kk) {
                bf8 vb = *(const bf8*)((const char*)Vt + swz_addr(c*16 + lcol, kk*64 + grp*16));
                acc[c] = __builtin_amdgcn_mfma_f32_16x16x32_bf16(pA[kk], vb, acc[c], 0, 0, 0);
            }
        }
    }

    // ---- epilogue ----
    float inv[4];
    #pragma unroll
    for (int reg = 0; reg < 4; ++reg) inv[reg] = 1.f / l_run[reg];
    #pragma unroll
    for (int c = 0; c < 4; ++c) {
        #pragma unroll
        for (int reg = 0; reg < 4; ++reg) {
            size_t o = ((size_t)(bS + i0 + w*16 + grp*4 + reg)) * D_MODEL + n64 + c*16 + lcol;
            av[o] = acc[c][reg] * inv[reg];
        }
    }
}

// ---------------------------------------------------------------------------
// LayerNorm(query + attn_out) * g + b
// ---------------------------------------------------------------------------
__global__ __launch_bounds__(256)
void ln_kernel(const float* __restrict__ query, const float* __restrict__ ao,
               const float* __restrict__ gam, const float* __restrict__ bet,
               float* __restrict__ out)
{
    int row = blockIdx.x;
    int tid = threadIdx.x;
    size_t base = (size_t)row * D_MODEL;
    float xv[3];
    float s = 0.f, sq = 0.f;
    #pragma unroll
    for (int k = 0; k < 3; ++k) {
        int c = tid + k * 256;
        float v = query[base + c] + ao[base + c];
        xv[k] = v; s += v; sq += v * v;
    }
    for (int off = 32; off > 0; off >>= 1) {
        s  += __shfl_down(s, off);
        sq += __shfl_down(sq, off);
    }
    __shared__ float rs[4], rq[4];
    __shared__ float mean_s, inv_s;
    int wid = tid >> 6, lane = tid & 63;
    if (lane == 0) { rs[wid] = s; rq[wid] = sq; }
    __syncthreads();
    if (tid == 0) {
        float S0 = rs[0] + rs[1] + rs[2] + rs[3];
        float Q0 = rq[0] + rq[1] + rq[2] + rq[3];
        float mean = S0 / (float)D_MODEL;
        float var  = Q0 / (float)D_MODEL - mean * mean;
        mean_s = mean;
        inv_s  = rsqrtf(var + LN_EPSF);
    }
    __syncthreads();
    float mean = mean_s, inv = inv_s;
    #pragma unroll
    for (int k = 0; k < 3; ++k) {
        int c = tid + k * 256;
        out[base + c] = (xv[k] - mean) * inv * gam[c] + bet[c];
    }
}

// ---------------------------------------------------------------------------
extern "C" void kernel_launch(void* const* d_in, const int* in_sizes, int n_in,
                              void* d_out, int out_size, void* d_ws, size_t ws_size,
                              hipStream_t stream)
{
    const float* query = (const float*)d_in[0];
    const float* key   = (const float*)d_in[1];
    const float* value = (const float*)d_in[2];
    const float* r     = (const float*)d_in[3];
    const void*  ttm   = d_in[4];
    const int*   amask = (const int*)d_in[5];
    const float* cls   = (const float*)d_in[6];
    const float* Wq    = (const float*)d_in[7];
    const float* Wk    = (const float*)d_in[8];
    const float* bk    = (const float*)d_in[9];
    const float* Wv    = (const float*)d_in[10];
    const float* bv    = (const float*)d_in[11];
    const float* Wpost = (const float*)d_in[12];
    const float* bpost = (const float*)d_in[13];
    const float* ln_g  = (const float*)d_in[14];
    const float* ln_b  = (const float*)d_in[15];
    const float* rwb   = (const float*)d_in[16];
    const float* rrb   = (const float*)d_in[17];
    const float* rker  = (const float*)d_in[18];
    const float* rsb   = (const float*)d_in[19];
    const float* seg   = (const float*)d_in[20];

    char* wsb = (char*)d_ws;
    __bf16* qh  = (__bf16*)(wsb);                    //  6,291,456 B
    __bf16* kh  = (__bf16*)(wsb + 6291456);
    __bf16* vh  = (__bf16*)(wsb + 12582912);
    __bf16* rhd = (__bf16*)(wsb + 18874368);         //  3,144,192 B (pad to 3,145,728)
    float*  tt  = (float*) (wsb + 22020096);         //    393,216 B
    float*  av  = (float*) (wsb + 22413312);         // 12,582,912 B
    float*  ao  = (float*) (wsb + 34996224);         // 12,582,912 B
    int*    flag = (int*)  (wsb + 47579136);

    detect_kernel<<<1, 64, 0, stream>>>((const unsigned char*)ttm, flag);

    dim3 gproj(12, 64);
    gemm_kernel<<<gproj, 256, 0, stream>>>(query, Wq, nullptr, qh, 4096, 768, 768, SCALE, 0, 1);
    gemm_kernel<<<gproj, 256, 0, stream>>>(key,   Wk, bk,      kh, 4096, 768, 768, 1.f, 1, 1);
    gemm_kernel<<<gproj, 256, 0, stream>>>(value, Wv, bv,      vh, 4096, 768, 768, 1.f, 1, 1);
    dim3 grh(12, 32);
    gemm_kernel<<<grh, 256, 0, stream>>>(r, rker, nullptr, rhd, 2047, 768, 768, 1.f, 0, 1);

    ttbias_kernel<<<384, 256, 0, stream>>>(qh, rsb, seg, tt);

    dim3 gattn(16, 12, 4);
    attn_kernel<<<gattn, 256, 0, stream>>>(qh, kh, vh, rhd, tt, cls, ttm, amask,
                                           rwb, rrb, flag, av);

    gemm_kernel<<<gproj, 256, 0, stream>>>(av, Wpost, bpost, ao, 4096, 768, 768, 1.f, 1, 0);

    ln_kernel<<<4096, 256, 0, stream>>>(query, ao, ln_g, ln_b, (float*)d_out);
}

// Round 4
// 419.873 us; speedup vs baseline: 4.0375x; 1.5861x over previous
//
#include <hip/hip_runtime.h>
#include <hip/hip_bf16.h>

#define S_LEN   1024
#define D_MODEL 768
#define N_HEAD  12
#define D_HEAD  64
#define BATCH   4
#define T_LEN   2047      // 2*S-1
#define INF_VAL 1000000.0f
#define SCALE   0.125f    // 1/sqrt(64)
#define LN_EPSF 1e-9f

typedef __attribute__((ext_vector_type(8))) __bf16 bf8;
typedef __attribute__((ext_vector_type(4))) __bf16 bf4;
typedef __attribute__((ext_vector_type(4))) float  f32x4;

// byte-address XOR swizzle for 128B-stride LDS rows
__device__ __forceinline__ int swz_addr(int row, int byte_in_row) {
    return ((row << 7) + byte_in_row) ^ ((row & 7) << 4);
}

// ---------------------------------------------------------------------------
// detect whether token_type_mat was pushed as int32 (1) or int8/bool (0)
// ---------------------------------------------------------------------------
__global__ void detect_kernel(const unsigned char* __restrict__ p, int* __restrict__ flag)
{
    if (threadIdx.x == 0 && blockIdx.x == 0) {
        int nz = 0;
        for (int k = 0; k < 4096; k += 4)
            nz += (p[k+1] != 0) + (p[k+2] != 0) + (p[k+3] != 0);
        *flag = (nz == 0) ? 1 : 0;
    }
}

// ---------------------------------------------------------------------------
// Wt[n][k] = (bf16) W[k][n]   (both 768-multiples; grid (N/64, K/64))
// ---------------------------------------------------------------------------
__global__ __launch_bounds__(256)
void wtrans_kernel(const float* __restrict__ W, __bf16* __restrict__ Wt, int K, int N)
{
    __shared__ float tile[64][65];
    int tid = threadIdx.x;
    int r = tid >> 4, c4 = (tid & 15) * 4;
    int k0 = blockIdx.y * 64, n0 = blockIdx.x * 64;
    #pragma unroll
    for (int rep = 0; rep < 4; ++rep) {
        int row = rep * 16 + r;
        float4 v = *(const float4*)(W + (size_t)(k0 + row) * N + n0 + c4);
        tile[row][c4+0] = v.x; tile[row][c4+1] = v.y;
        tile[row][c4+2] = v.z; tile[row][c4+3] = v.w;
    }
    __syncthreads();
    #pragma unroll
    for (int rep = 0; rep < 4; ++rep) {
        int row = rep * 16 + r;             // output n = n0 + row
        bf4 o;
        #pragma unroll
        for (int j = 0; j < 4; ++j) o[j] = (__bf16)tile[c4 + j][row];
        *(bf4*)(Wt + (size_t)(n0 + row) * K + k0 + c4) = o;
    }
}

// ---------------------------------------------------------------------------
// MFMA GEMM: C[M,N] = A[M,K] @ Bt[N,K]^T * scale (+ bias)
// A fp32 (a_bf16=0, converted in staging) or bf16 (a_bf16=1); Bt bf16 [N,K].
// 128x128 tile, BK=64, 4 waves (2x2), 16x16x32 MFMA, XOR-swizzled LDS.
// ---------------------------------------------------------------------------
__global__ __launch_bounds__(256)
void mfma_gemm(const void* __restrict__ A, const __bf16* __restrict__ Bt,
               const float* __restrict__ bias, void* __restrict__ C,
               int M, int N, int K, float scale, int has_bias, int a_bf16, int out_bf16)
{
    __shared__ __align__(16) __bf16 As[128 * 64];
    __shared__ __align__(16) __bf16 Bs[128 * 64];

    int tid = threadIdx.x;
    int lane = tid & 63, w = tid >> 6;
    int grp = lane >> 4, lcol = lane & 15;
    int wm = w >> 1, wn = w & 1;
    int m0 = blockIdx.y * 128, n0 = blockIdx.x * 128;

    f32x4 acc[4][4] = {};

    for (int kt = 0; kt < K; kt += 64) {
        __syncthreads();
        // ---- stage A (fp32->bf16 or bf16 passthrough) ----
        #pragma unroll
        for (int rep = 0; rep < 4; ++rep) {
            int id = rep * 256 + tid;
            int row = id >> 3, ch = id & 7;
            int gm = m0 + row; if (gm >= M) gm = M - 1;
            bf8 v;
            if (a_bf16) {
                v = *(const bf8*)((const __bf16*)A + (size_t)gm * K + kt + ch * 8);
            } else {
                const float* ap = (const float*)A + (size_t)gm * K + kt + ch * 8;
                float4 f0 = *(const float4*)ap;
                float4 f1 = *(const float4*)(ap + 4);
                v[0] = (__bf16)f0.x; v[1] = (__bf16)f0.y; v[2] = (__bf16)f0.z; v[3] = (__bf16)f0.w;
                v[4] = (__bf16)f1.x; v[5] = (__bf16)f1.y; v[6] = (__bf16)f1.z; v[7] = (__bf16)f1.w;
            }
            *(bf8*)((char*)As + swz_addr(row, ch * 16)) = v;
        }
        // ---- stage B ----
        #pragma unroll
        for (int rep = 0; rep < 4; ++rep) {
            int id = rep * 256 + tid;
            int row = id >> 3, ch = id & 7;
            bf8 v = *(const bf8*)(Bt + (size_t)(n0 + row) * K + kt + ch * 8);
            *(bf8*)((char*)Bs + swz_addr(row, ch * 16)) = v;
        }
        __syncthreads();
        // ---- compute ----
        #pragma unroll
        for (int kk = 0; kk < 2; ++kk) {
            bf8 a[4], bb[4];
            #pragma unroll
            for (int mi = 0; mi < 4; ++mi)
                a[mi] = *(const bf8*)((const char*)As + swz_addr(wm * 64 + mi * 16 + lcol, kk * 64 + grp * 16));
            #pragma unroll
            for (int ni = 0; ni < 4; ++ni)
                bb[ni] = *(const bf8*)((const char*)Bs + swz_addr(wn * 64 + ni * 16 + lcol, kk * 64 + grp * 16));
            #pragma unroll
            for (int mi = 0; mi < 4; ++mi) {
                #pragma unroll
                for (int ni = 0; ni < 4; ++ni)
                    acc[mi][ni] = __builtin_amdgcn_mfma_f32_16x16x32_bf16(a[mi], bb[ni], acc[mi][ni], 0, 0, 0);
            }
        }
    }

    // ---- epilogue ----
    #pragma unroll
    for (int ni = 0; ni < 4; ++ni) {
        int col = n0 + wn * 64 + ni * 16 + lcol;
        float bval = has_bias ? bias[col] : 0.f;
        #pragma unroll
        for (int mi = 0; mi < 4; ++mi) {
            int rbase = m0 + wm * 64 + mi * 16 + grp * 4;
            #pragma unroll
            for (int reg = 0; reg < 4; ++reg) {
                int row = rbase + reg;
                if (row < M) {
                    float vv = acc[mi][ni][reg] * scale + bval;
                    if (out_bf16) ((__bf16*)C)[(size_t)row * N + col] = (__bf16)vv;
                    else          ((float*)C)[(size_t)row * N + col] = vv;
                }
            }
        }
    }
}

// ---------------------------------------------------------------------------
// tt[(b*S+i)*NH*2 + n*2 + s2] = sum_h (qh + r_s_bias*scale) * seg_embed
// ---------------------------------------------------------------------------
__global__ __launch_bounds__(256)
void ttbias_kernel(const __bf16* __restrict__ qh, const float* __restrict__ rsb,
                   const float* __restrict__ seg, float* __restrict__ tt)
{
    int idx = blockIdx.x * 256 + threadIdx.x;
    if (idx >= BATCH * S_LEN * N_HEAD * 2) return;
    int s2  = idx & 1;
    int n   = (idx >> 1) % N_HEAD;
    int row = idx / (2 * N_HEAD);
    const __bf16* q  = qh  + (size_t)row * D_MODEL + n * D_HEAD;
    const float* sg = seg + ((size_t)s2 * N_HEAD + n) * D_HEAD;
    const float* rb = rsb + n * D_HEAD;
    float s = 0.f;
    for (int h = 0; h < D_HEAD; ++h) s += ((float)q[h] + rb[h] * SCALE) * sg[h];
    tt[idx] = s;
}

// ---------------------------------------------------------------------------
// MFMA fused attention. grid (16, 12, 4), 256 thr. 64 q-rows/block, 16/wave.
// ---------------------------------------------------------------------------
__global__ __launch_bounds__(256)
void attn_kernel(const __bf16* __restrict__ qh, const __bf16* __restrict__ kh,
                 const __bf16* __restrict__ vh, const __bf16* __restrict__ rhd,
                 const float* __restrict__ tt, const float* __restrict__ cls,
                 const void* __restrict__ ttm, const int* __restrict__ amask,
                 const float* __restrict__ rwb, const float* __restrict__ rrb,
                 const int* __restrict__ flag, __bf16* __restrict__ av)
{
    __shared__ __align__(16) __bf16 Kt[64*64];       // [j][h]
    __shared__ __align__(16) __bf16 Vt[64*64];       // [d][j]  (transposed)
    __shared__ __align__(16) __bf16 Rw[128*64];      // [r][h]
    __shared__ __align__(16) __bf16 Ps[4*16*64];     // per-wave P [il][jl]
    __shared__ __align__(16) __bf16 poss[4*16*84];   // per-wave pos band, stride 84
    __shared__ __align__(16) __bf16 clss[64*68];     // stride 68
    __shared__ __align__(16) __bf16 tss[64*68];      // stride 68

    int tid = threadIdx.x;
    int i0 = blockIdx.x * 64;
    int n  = blockIdx.y;
    int b  = blockIdx.z;
    int bS = b * S_LEN;
    int n64 = n * D_HEAD;
    int is_i32 = *flag;

    int lane = tid & 63, w = tid >> 6;
    int grp = lane >> 4, lcol = lane & 15;

    // ---- Q fragments ----
    bf8 qwA[2], qrA[2];
    {
        size_t qrow = (size_t)(bS + i0 + w*16 + lcol) * D_MODEL + n64;
        #pragma unroll
        for (int kk = 0; kk < 2; ++kk) {
            int kb = kk*32 + grp*8;
            bf8 qv = *(const bf8*)(qh + qrow + kb);
            const float* wbp = rwb + n64 + kb;
            const float* rbp = rrb + n64 + kb;
            #pragma unroll
            for (int q = 0; q < 8; ++q) {
                float f = (float)qv[q];
                qwA[kk][q] = (__bf16)(f + wbp[q] * SCALE);
                qrA[kk][q] = (__bf16)(f + rbp[q] * SCALE);
            }
        }
    }

    // ---- relative-shift edge fixup value: qr_row1 . r_head[0] ----
    float fixv = 0.f;
    if (i0 == 0) {
        float qv = (float)qh[((size_t)(bS + 1)) * D_MODEL + n64 + lane] + rrb[n64 + lane] * SCALE;
        float rv = (float)rhd[n64 + lane];
        float t = qv * rv;
        #pragma unroll
        for (int m = 32; m; m >>= 1) t += __shfl_xor(t, m, 64);
        fixv = t;
    }
    bool fix = (i0 == 0 && w == 0 && lane == 15);

    float m_run[4] = {-1e30f, -1e30f, -1e30f, -1e30f};
    float l_run[4] = {0.f, 0.f, 0.f, 0.f};
    f32x4 acc[4] = {};
    const f32x4 zero4 = {0.f, 0.f, 0.f, 0.f};

    for (int jt = 0; jt < 16; ++jt) {
        int j0 = jt * 64;
        __syncthreads();

        // ---- stage K tile ----
        #pragma unroll
        for (int rep = 0; rep < 2; ++rep) {
            int idx = rep*256 + tid;
            int row = idx >> 3;
            int c8  = (idx & 7) * 8;
            bf8 v = *(const bf8*)(kh + (size_t)(bS + j0 + row) * D_MODEL + n64 + c8);
            *(bf8*)((char*)Kt + swz_addr(row, c8*2)) = v;
        }
        // ---- stage V transposed ----
        #pragma unroll
        for (int rep = 0; rep < 2; ++rep) {
            int idx = rep*256 + tid;
            int row = idx >> 3;               // j
            int c8  = (idx & 7) * 8;          // d base
            bf8 v = *(const bf8*)(vh + (size_t)(bS + j0 + row) * D_MODEL + n64 + c8);
            #pragma unroll
            for (int q = 0; q < 8; ++q) {
                int d = c8 + q;
                *((__bf16*)((char*)Vt + swz_addr(d, row*2))) = v[q];
            }
        }
        // ---- stage r_head window ----
        int w0 = j0 - i0 + 961;
        #pragma unroll
        for (int rep = 0; rep < 4; ++rep) {
            int idx = rep*256 + tid;
            int row = idx >> 3;
            int c8  = (idx & 7) * 8;
            int t = w0 + row;
            bf8 v = {};
            if (t >= 0 && t < T_LEN)
                v = *(const bf8*)(rhd + (size_t)t * D_MODEL + n64 + c8);
            *(bf8*)((char*)Rw + swz_addr(row, c8*2)) = v;
        }
        // ---- stage cls + ts tiles ----
        #pragma unroll
        for (int rep = 0; rep < 4; ++rep) {
            int idx = rep*256 + tid;
            int row = idx >> 4;
            int c4  = (idx & 15) * 4;
            int gi = i0 + row, gj = j0 + c4;
            float4 cv = *(const float4*)(cls + (size_t)gi * S_LEN + gj);
            const float* ttrow = tt + (((size_t)(bS + gi)) * N_HEAD + n) * 2;
            float t0 = ttrow[0], t1 = ttrow[1];
            float cc[4] = {cv.x, cv.y, cv.z, cv.w};
            bf4 cw, tw;
            #pragma unroll
            for (int q = 0; q < 4; ++q) {
                size_t toff = ((size_t)(bS + gi)) * S_LEN + gj + q;
                int tm = is_i32 ? ((const int*)ttm)[toff]
                                : (int)((const unsigned char*)ttm)[toff];
                float am = (float)amask[b * S_LEN + gj + q];
                cw[q] = (__bf16)cc[q];
                tw[q] = (__bf16)(cc[q] * (tm ? t1 : t0) - INF_VAL * (1.f - am));
            }
            int base = row * 68 + c4;
            *(bf4*)&clss[base] = cw;
            *(bf4*)&tss[base]  = tw;
        }
        __syncthreads();

        // ---- content scores ----
        f32x4 sc_[4] = {zero4, zero4, zero4, zero4};
        #pragma unroll
        for (int c = 0; c < 4; ++c) {
            #pragma unroll
            for (int kk = 0; kk < 2; ++kk) {
                bf8 kb = *(const bf8*)((const char*)Kt + swz_addr(c*16 + lcol, kk*64 + grp*16));
                sc_[c] = __builtin_amdgcn_mfma_f32_16x16x32_bf16(qwA[kk], kb, sc_[c], 0, 0, 0);
            }
        }
        // ---- positional: 5 window tiles ----
        int a0 = 3 - w;
        f32x4 pacc[5] = {zero4, zero4, zero4, zero4, zero4};
        #pragma unroll
        for (int pa = 0; pa < 5; ++pa) {
            int ar = (a0 + pa) * 16 + lcol;
            #pragma unroll
            for (int kk = 0; kk < 2; ++kk) {
                bf8 rb = *(const bf8*)((const char*)Rw + swz_addr(ar, kk*64 + grp*16));
                pacc[pa] = __builtin_amdgcn_mfma_f32_16x16x32_bf16(qrA[kk], rb, pacc[pa], 0, 0, 0);
            }
        }
        __bf16* pw = poss + w * 16 * 84;
        #pragma unroll
        for (int pa = 0; pa < 5; ++pa) {
            #pragma unroll
            for (int reg = 0; reg < 4; ++reg)
                pw[(grp*4 + reg) * 84 + pa*16 + lcol] = (__bf16)pacc[pa][reg];
        }
        asm volatile("s_waitcnt lgkmcnt(0)" ::: "memory");
        __builtin_amdgcn_sched_barrier(0);

        // ---- assemble scores ----
        float sv[4][4];
        #pragma unroll
        for (int c = 0; c < 4; ++c) {
            int jl = c*16 + lcol;
            #pragma unroll
            for (int reg = 0; reg < 4; ++reg) {
                int il = grp*4 + reg;
                int rr = jl - il + 15;
                float pv = (float)pw[il * 84 + rr];
                if (fix && jt == 15 && c == 3 && reg == 0) pv = fixv;
                int rb2 = (w*16 + il) * 68 + jl;
                float clv = (float)clss[rb2];
                float tsv = (float)tss[rb2];
                sv[c][reg] = sc_[c][reg] + clv * pv + tsv;
            }
        }

        // ---- online softmax ----
        float mx[4], alpha[4], rs[4];
        #pragma unroll
        for (int reg = 0; reg < 4; ++reg)
            mx[reg] = fmaxf(fmaxf(sv[0][reg], sv[1][reg]), fmaxf(sv[2][reg], sv[3][reg]));
        #pragma unroll
        for (int msk = 1; msk < 16; msk <<= 1) {
            #pragma unroll
            for (int reg = 0; reg < 4; ++reg)
                mx[reg] = fmaxf(mx[reg], __shfl_xor(mx[reg], msk, 64));
        }
        #pragma unroll
        for (int reg = 0; reg < 4; ++reg) {
            float mn = fmaxf(m_run[reg], mx[reg]);
            alpha[reg] = __expf(m_run[reg] - mn);
            m_run[reg] = mn;
            rs[reg] = 0.f;
        }
        __bf16* psw = Ps;
        #pragma unroll
        for (int c = 0; c < 4; ++c) {
            int jl = c*16 + lcol;
            #pragma unroll
            for (int reg = 0; reg < 4; ++reg) {
                int il = grp*4 + reg;
                float p = __expf(sv[c][reg] - m_run[reg]);
                rs[reg] += p;
                *((__bf16*)((char*)psw + w*2048 + swz_addr(il, jl*2))) = (__bf16)p;
            }
        }
        #pragma unroll
        for (int msk = 1; msk < 16; msk <<= 1) {
            #pragma unroll
            for (int reg = 0; reg < 4; ++reg)
                rs[reg] += __shfl_xor(rs[reg], msk, 64);
        }
        #pragma unroll
        for (int reg = 0; reg < 4; ++reg)
            l_run[reg] = l_run[reg] * alpha[reg] + rs[reg];
        #pragma unroll
        for (int c = 0; c < 4; ++c) {
            #pragma unroll
            for (int reg = 0; reg < 4; ++reg) acc[c][reg] *= alpha[reg];
        }
        asm volatile("s_waitcnt lgkmcnt(0)" ::: "memory");
        __builtin_amdgcn_sched_barrier(0);

        // ---- PV ----
        bf8 pA[2];
        #pragma unroll
        for (int kk = 0; kk < 2; ++kk)
            pA[kk] = *(const bf8*)((const char*)psw + w*2048 + swz_addr(lcol, kk*64 + grp*16));
        #pragma unroll
        for (int c = 0; c < 4; ++c) {
            #pragma unroll
            for (int kk = 0; kk < 2; ++kk) {
                bf8 vb = *(const bf8*)((const char*)Vt + swz_addr(c*16 + lcol, kk*64 + grp*16));
                acc[c] = __builtin_amdgcn_mfma_f32_16x16x32_bf16(pA[kk], vb, acc[c], 0, 0, 0);
            }
        }
    }

    // ---- epilogue (bf16 out) ----
    float inv[4];
    #pragma unroll
    for (int reg = 0; reg < 4; ++reg) inv[reg] = 1.f / l_run[reg];
    #pragma unroll
    for (int c = 0; c < 4; ++c) {
        #pragma unroll
        for (int reg = 0; reg < 4; ++reg) {
            size_t o = ((size_t)(bS + i0 + w*16 + grp*4 + reg)) * D_MODEL + n64 + c*16 + lcol;
            av[o] = (__bf16)(acc[c][reg] * inv[reg]);
        }
    }
}

// ---------------------------------------------------------------------------
// LayerNorm(query + attn_out) * g + b
// ---------------------------------------------------------------------------
__global__ __launch_bounds__(256)
void ln_kernel(const float* __restrict__ query, const float* __restrict__ ao,
               const float* __restrict__ gam, const float* __restrict__ bet,
               float* __restrict__ out)
{
    int row = blockIdx.x;
    int tid = threadIdx.x;
    size_t base = (size_t)row * D_MODEL;
    float xv[3];
    float s = 0.f, sq = 0.f;
    #pragma unroll
    for (int k = 0; k < 3; ++k) {
        int c = tid + k * 256;
        float v = query[base + c] + ao[base + c];
        xv[k] = v; s += v; sq += v * v;
    }
    for (int off = 32; off > 0; off >>= 1) {
        s  += __shfl_down(s, off);
        sq += __shfl_down(sq, off);
    }
    __shared__ float rs[4], rq[4];
    __shared__ float mean_s, inv_s;
    int wid = tid >> 6, lane = tid & 63;
    if (lane == 0) { rs[wid] = s; rq[wid] = sq; }
    __syncthreads();
    if (tid == 0) {
        float S0 = rs[0] + rs[1] + rs[2] + rs[3];
        float Q0 = rq[0] + rq[1] + rq[2] + rq[3];
        float mean = S0 / (float)D_MODEL;
        float var  = Q0 / (float)D_MODEL - mean * mean;
        mean_s = mean;
        inv_s  = rsqrtf(var + LN_EPSF);
    }
    __syncthreads();
    float mean = mean_s, inv = inv_s;
    #pragma unroll
    for (int k = 0; k < 3; ++k) {
        int c = tid + k * 256;
        out[base + c] = (xv[k] - mean) * inv * gam[c] + bet[c];
    }
}

// ---------------------------------------------------------------------------
extern "C" void kernel_launch(void* const* d_in, const int* in_sizes, int n_in,
                              void* d_out, int out_size, void* d_ws, size_t ws_size,
                              hipStream_t stream)
{
    const float* query = (const float*)d_in[0];
    const float* key   = (const float*)d_in[1];
    const float* value = (const float*)d_in[2];
    const float* r     = (const float*)d_in[3];
    const void*  ttm   = d_in[4];
    const int*   amask = (const int*)d_in[5];
    const float* cls   = (const float*)d_in[6];
    const float* Wq    = (const float*)d_in[7];
    const float* Wk    = (const float*)d_in[8];
    const float* bk    = (const float*)d_in[9];
    const float* Wv    = (const float*)d_in[10];
    const float* bv    = (const float*)d_in[11];
    const float* Wpost = (const float*)d_in[12];
    const float* bpost = (const float*)d_in[13];
    const float* ln_g  = (const float*)d_in[14];
    const float* ln_b  = (const float*)d_in[15];
    const float* rwb   = (const float*)d_in[16];
    const float* rrb   = (const float*)d_in[17];
    const float* rker  = (const float*)d_in[18];
    const float* rsb   = (const float*)d_in[19];
    const float* seg   = (const float*)d_in[20];

    char* wsb = (char*)d_ws;
    __bf16* qh  = (__bf16*)(wsb);                    //  6,291,456
    __bf16* kh  = (__bf16*)(wsb + 6291456);          //  6,291,456
    __bf16* vh  = (__bf16*)(wsb + 12582912);         //  6,291,456
    __bf16* rhd = (__bf16*)(wsb + 18874368);         //  3,145,728 (incl pad)
    float*  tt  = (float*) (wsb + 22020096);         //    393,216
    __bf16* av  = (__bf16*)(wsb + 22413312);         //  6,291,456
    float*  ao  = (float*) (wsb + 28704768);         // 12,582,912
    __bf16* Wqt = (__bf16*)(wsb + 41287680);         //  1,179,648
    __bf16* Wkt = (__bf16*)(wsb + 42467328);
    __bf16* Wvt = (__bf16*)(wsb + 43646976);
    __bf16* Wpt = (__bf16*)(wsb + 44826624);
    __bf16* rkt = (__bf16*)(wsb + 46006272);
    int*    flag = (int*)  (wsb + 47185920);

    detect_kernel<<<1, 64, 0, stream>>>((const unsigned char*)ttm, flag);

    dim3 gtr(12, 12);
    wtrans_kernel<<<gtr, 256, 0, stream>>>(Wq,    Wqt, 768, 768);
    wtrans_kernel<<<gtr, 256, 0, stream>>>(Wk,    Wkt, 768, 768);
    wtrans_kernel<<<gtr, 256, 0, stream>>>(Wv,    Wvt, 768, 768);
    wtrans_kernel<<<gtr, 256, 0, stream>>>(Wpost, Wpt, 768, 768);
    wtrans_kernel<<<gtr, 256, 0, stream>>>(rker,  rkt, 768, 768);

    dim3 gproj(6, 32);   // N/128, M/128
    mfma_gemm<<<gproj, 256, 0, stream>>>(query, Wqt, nullptr, qh, 4096, 768, 768, SCALE, 0, 0, 1);
    mfma_gemm<<<gproj, 256, 0, stream>>>(key,   Wkt, bk,      kh, 4096, 768, 768, 1.f,  1, 0, 1);
    mfma_gemm<<<gproj, 256, 0, stream>>>(value, Wvt, bv,      vh, 4096, 768, 768, 1.f,  1, 0, 1);
    dim3 grh(6, 16);
    mfma_gemm<<<grh, 256, 0, stream>>>(r, rkt, nullptr, rhd, 2047, 768, 768, 1.f, 0, 0, 1);

    ttbias_kernel<<<384, 256, 0, stream>>>(qh, rsb, seg, tt);

    dim3 gattn(16, 12, 4);
    attn_kernel<<<gattn, 256, 0, stream>>>(qh, kh, vh, rhd, tt, cls, ttm, amask,
                                           rwb, rrb, flag, av);

    mfma_gemm<<<gproj, 256, 0, stream>>>(av, Wpt, bpost, ao, 4096, 768, 768, 1.f, 1, 1, 0);

    ln_kernel<<<4096, 256, 0, stream>>>(query, ao, ln_g, ln_b, (float*)d_out);
}

// Round 5
// 238.783 us; speedup vs baseline: 7.0995x; 1.7584x over previous
//
#include <hip/hip_runtime.h>
#include <hip/hip_bf16.h>

#define S_LEN   1024
#define D_MODEL 768
#define N_HEAD  12
#define D_HEAD  64
#define BATCH   4
#define T_LEN   2047      // 2*S-1
#define INF_VAL 1000000.0f
#define SCALE   0.125f    // 1/sqrt(64)
#define LN_EPSF 1e-9f

typedef __attribute__((ext_vector_type(8))) __bf16 bf8;
typedef __attribute__((ext_vector_type(4))) __bf16 bf4;
typedef __attribute__((ext_vector_type(4))) float  f32x4;

// byte-address XOR swizzle for 128B-stride LDS rows
__device__ __forceinline__ int swz_addr(int row, int byte_in_row) {
    return ((row << 7) + byte_in_row) ^ ((row & 7) << 4);
}

// ---------------------------------------------------------------------------
// detect whether token_type_mat was pushed as int32 (1) or int8/bool (0)
// ---------------------------------------------------------------------------
__global__ void detect_kernel(const unsigned char* __restrict__ p, int* __restrict__ flag)
{
    int lane = threadIdx.x;          // 64 threads
    int nz = 0;
    int base = lane * 64;
    for (int k = base; k < base + 64; k += 4)
        nz += (p[k+1] != 0) + (p[k+2] != 0) + (p[k+3] != 0);
    unsigned long long m = __ballot(nz != 0);
    if (lane == 0) *flag = (m == 0ull) ? 1 : 0;
}

// ---------------------------------------------------------------------------
// selbit[idx] = token_type_mat[idx] ? 1 : 0   (8 elements/thread)
// ---------------------------------------------------------------------------
__global__ __launch_bounds__(256)
void prep_sel(const void* __restrict__ ttm, const int* __restrict__ flag,
              unsigned char* __restrict__ selbit)
{
    size_t idx = ((size_t)blockIdx.x * 256 + threadIdx.x) * 8;
    unsigned long long out = 0;
    if (*flag) {
        const int* ip = (const int*)ttm + idx;
        int4 a = *(const int4*)ip;
        int4 b = *(const int4*)(ip + 4);
        out  = (a.x ? 1ull : 0)       | (a.y ? 1ull : 0) << 8
             | (a.z ? 1ull : 0) << 16 | (a.w ? 1ull : 0) << 24
             | (b.x ? 1ull : 0) << 32 | (b.y ? 1ull : 0) << 40
             | (b.z ? 1ull : 0) << 48 | (b.w ? 1ull : 0) << 56;
    } else {
        unsigned long long raw = *(const unsigned long long*)((const unsigned char*)ttm + idx);
        #pragma unroll
        for (int i = 0; i < 8; ++i)
            out |= (((raw >> (8*i)) & 0xffull) ? 1ull : 0) << (8*i);
    }
    *(unsigned long long*)(selbit + idx) = out;
}

// ---------------------------------------------------------------------------
// clsb = bf16(cls);  maskadd[b*S+j] = -INF*(1-amask)
// ---------------------------------------------------------------------------
__global__ __launch_bounds__(256)
void clsb_prep(const float* __restrict__ cls, const int* __restrict__ amask,
               __bf16* __restrict__ clsb, float* __restrict__ maskadd)
{
    size_t idx = ((size_t)blockIdx.x * 256 + threadIdx.x) * 8;
    const float* p = cls + idx;
    float4 a = *(const float4*)p;
    float4 b = *(const float4*)(p + 4);
    bf8 o;
    o[0]=(__bf16)a.x; o[1]=(__bf16)a.y; o[2]=(__bf16)a.z; o[3]=(__bf16)a.w;
    o[4]=(__bf16)b.x; o[5]=(__bf16)b.y; o[6]=(__bf16)b.z; o[7]=(__bf16)b.w;
    *(bf8*)(clsb + idx) = o;
    if (blockIdx.x == 0) {
        for (int j = threadIdx.x; j < BATCH * S_LEN; j += 256)
            maskadd[j] = -INF_VAL * (1.f - (float)amask[j]);
    }
}

// ---------------------------------------------------------------------------
// Wt[n][k] = (bf16) W[k][n]; fused over 5 weight matrices via blockIdx.z
// ---------------------------------------------------------------------------
__global__ __launch_bounds__(256)
void wtrans_kernel(const float* __restrict__ W0, const float* __restrict__ W1,
                   const float* __restrict__ W2, const float* __restrict__ W3,
                   const float* __restrict__ W4,
                   __bf16* __restrict__ T0, __bf16* __restrict__ T1,
                   __bf16* __restrict__ T2, __bf16* __restrict__ T3,
                   __bf16* __restrict__ T4)
{
    const float* W; __bf16* Wt;
    switch (blockIdx.z) {
        case 0: W = W0; Wt = T0; break;
        case 1: W = W1; Wt = T1; break;
        case 2: W = W2; Wt = T2; break;
        case 3: W = W3; Wt = T3; break;
        default: W = W4; Wt = T4; break;
    }
    const int K = 768, N = 768;
    __shared__ float tile[64][65];
    int tid = threadIdx.x;
    int r = tid >> 4, c4 = (tid & 15) * 4;
    int k0 = blockIdx.y * 64, n0 = blockIdx.x * 64;
    #pragma unroll
    for (int rep = 0; rep < 4; ++rep) {
        int row = rep * 16 + r;
        float4 v = *(const float4*)(W + (size_t)(k0 + row) * N + n0 + c4);
        tile[row][c4+0] = v.x; tile[row][c4+1] = v.y;
        tile[row][c4+2] = v.z; tile[row][c4+3] = v.w;
    }
    __syncthreads();
    #pragma unroll
    for (int rep = 0; rep < 4; ++rep) {
        int row = rep * 16 + r;
        bf4 o;
        #pragma unroll
        for (int j = 0; j < 4; ++j) o[j] = (__bf16)tile[c4 + j][row];
        *(bf4*)(Wt + (size_t)(n0 + row) * K + k0 + c4) = o;
    }
}

// ---------------------------------------------------------------------------
// MFMA GEMM tile body: C[128 rows x 128 cols] at (m0,n0)
// ---------------------------------------------------------------------------
__device__ __forceinline__
void gemm_tile_body(const void* __restrict__ A, const __bf16* __restrict__ Bt,
                    const float* __restrict__ bias, void* __restrict__ C,
                    int M, int N, int K, float scale, int has_bias,
                    int a_bf16, int out_bf16, int m0, int n0,
                    __bf16* As, __bf16* Bs)
{
    int tid = threadIdx.x;
    int lane = tid & 63, w = tid >> 6;
    int grp = lane >> 4, lcol = lane & 15;
    int wm = w >> 1, wn = w & 1;

    f32x4 acc[4][4] = {};

    for (int kt = 0; kt < K; kt += 64) {
        __syncthreads();
        #pragma unroll
        for (int rep = 0; rep < 4; ++rep) {
            int id = rep * 256 + tid;
            int row = id >> 3, ch = id & 7;
            int gm = m0 + row; if (gm >= M) gm = M - 1;
            bf8 v;
            if (a_bf16) {
                v = *(const bf8*)((const __bf16*)A + (size_t)gm * K + kt + ch * 8);
            } else {
                const float* ap = (const float*)A + (size_t)gm * K + kt + ch * 8;
                float4 f0 = *(const float4*)ap;
                float4 f1 = *(const float4*)(ap + 4);
                v[0] = (__bf16)f0.x; v[1] = (__bf16)f0.y; v[2] = (__bf16)f0.z; v[3] = (__bf16)f0.w;
                v[4] = (__bf16)f1.x; v[5] = (__bf16)f1.y; v[6] = (__bf16)f1.z; v[7] = (__bf16)f1.w;
            }
            *(bf8*)((char*)As + swz_addr(row, ch * 16)) = v;
        }
        #pragma unroll
        for (int rep = 0; rep < 4; ++rep) {
            int id = rep * 256 + tid;
            int row = id >> 3, ch = id & 7;
            bf8 v = *(const bf8*)(Bt + (size_t)(n0 + row) * K + kt + ch * 8);
            *(bf8*)((char*)Bs + swz_addr(row, ch * 16)) = v;
        }
        __syncthreads();
        #pragma unroll
        for (int kk = 0; kk < 2; ++kk) {
            bf8 a[4], bb[4];
            #pragma unroll
            for (int mi = 0; mi < 4; ++mi)
                a[mi] = *(const bf8*)((const char*)As + swz_addr(wm * 64 + mi * 16 + lcol, kk * 64 + grp * 16));
            #pragma unroll
            for (int ni = 0; ni < 4; ++ni)
                bb[ni] = *(const bf8*)((const char*)Bs + swz_addr(wn * 64 + ni * 16 + lcol, kk * 64 + grp * 16));
            #pragma unroll
            for (int mi = 0; mi < 4; ++mi) {
                #pragma unroll
                for (int ni = 0; ni < 4; ++ni)
                    acc[mi][ni] = __builtin_amdgcn_mfma_f32_16x16x32_bf16(a[mi], bb[ni], acc[mi][ni], 0, 0, 0);
            }
        }
    }

    #pragma unroll
    for (int ni = 0; ni < 4; ++ni) {
        int col = n0 + wn * 64 + ni * 16 + lcol;
        float bval = has_bias ? bias[col] : 0.f;
        #pragma unroll
        for (int mi = 0; mi < 4; ++mi) {
            int rbase = m0 + wm * 64 + mi * 16 + grp * 4;
            #pragma unroll
            for (int reg = 0; reg < 4; ++reg) {
                int row = rbase + reg;
                if (row < M) {
                    float vv = acc[mi][ni][reg] * scale + bval;
                    if (out_bf16) ((__bf16*)C)[(size_t)row * N + col] = (__bf16)vv;
                    else          ((float*)C)[(size_t)row * N + col] = vv;
                }
            }
        }
    }
}

// ---------------------------------------------------------------------------
// All four projection GEMMs in one dispatch (z = 0:q 1:k 2:v 3:r)
// ---------------------------------------------------------------------------
__global__ __launch_bounds__(256)
void proj_gemm(const float* __restrict__ query, const float* __restrict__ key,
               const float* __restrict__ value, const float* __restrict__ r,
               const __bf16* __restrict__ Wqt, const __bf16* __restrict__ Wkt,
               const __bf16* __restrict__ Wvt, const __bf16* __restrict__ rkt,
               const float* __restrict__ bk, const float* __restrict__ bv,
               __bf16* __restrict__ qh, __bf16* __restrict__ kh,
               __bf16* __restrict__ vh, __bf16* __restrict__ rhd)
{
    __shared__ __align__(16) __bf16 As[128 * 64];
    __shared__ __align__(16) __bf16 Bs[128 * 64];
    int z = blockIdx.z;
    const float* A; const __bf16* Bt; const float* bias; __bf16* C;
    int M; float scale; int has_bias;
    if (z == 0)      { A = query; Bt = Wqt; bias = nullptr; C = qh;  M = 4096; scale = SCALE; has_bias = 0; }
    else if (z == 1) { A = key;   Bt = Wkt; bias = bk;      C = kh;  M = 4096; scale = 1.f;   has_bias = 1; }
    else if (z == 2) { A = value; Bt = Wvt; bias = bv;      C = vh;  M = 4096; scale = 1.f;   has_bias = 1; }
    else             { A = r;     Bt = rkt; bias = nullptr; C = rhd; M = 2047; scale = 1.f;   has_bias = 0; }
    int m0 = blockIdx.y * 128, n0 = blockIdx.x * 128;
    if (m0 >= M) return;
    gemm_tile_body(A, Bt, bias, C, M, 768, 768, scale, has_bias, 0, 1, m0, n0, As, Bs);
}

// ---------------------------------------------------------------------------
// post-projection GEMM (av bf16 -> ao fp32)
// ---------------------------------------------------------------------------
__global__ __launch_bounds__(256)
void post_gemm(const __bf16* __restrict__ av, const __bf16* __restrict__ Wpt,
               const float* __restrict__ bpost, float* __restrict__ ao)
{
    __shared__ __align__(16) __bf16 As[128 * 64];
    __shared__ __align__(16) __bf16 Bs[128 * 64];
    gemm_tile_body(av, Wpt, bpost, ao, 4096, 768, 768, 1.f, 1, 1, 0,
                   blockIdx.y * 128, blockIdx.x * 128, As, Bs);
}

// ---------------------------------------------------------------------------
// tt[(b*S+i)*NH*2 + n*2 + s2] = sum_h (qh + r_s_bias*scale) * seg_embed
// ---------------------------------------------------------------------------
__global__ __launch_bounds__(256)
void ttbias_kernel(const __bf16* __restrict__ qh, const float* __restrict__ rsb,
                   const float* __restrict__ seg, float* __restrict__ tt)
{
    int idx = blockIdx.x * 256 + threadIdx.x;
    if (idx >= BATCH * S_LEN * N_HEAD * 2) return;
    int s2  = idx & 1;
    int n   = (idx >> 1) % N_HEAD;
    int row = idx / (2 * N_HEAD);
    const __bf16* q  = qh  + (size_t)row * D_MODEL + n * D_HEAD;
    const float* sg = seg + ((size_t)s2 * N_HEAD + n) * D_HEAD;
    const float* rb = rsb + n * D_HEAD;
    float s = 0.f;
    for (int h = 0; h < D_HEAD; ++h) s += ((float)q[h] + rb[h] * SCALE) * sg[h];
    tt[idx] = s;
}

// ---------------------------------------------------------------------------
// MFMA fused attention. grid (16, 12, 4), 256 thr. 64 q-rows/block, 16/wave.
// LDS 50.5 KB -> 3 blocks/CU; grid 768 = exactly 3 rounds-free.
// ---------------------------------------------------------------------------
__global__ __launch_bounds__(256, 3)
void attn_kernel(const __bf16* __restrict__ qh, const __bf16* __restrict__ kh,
                 const __bf16* __restrict__ vh, const __bf16* __restrict__ rhd,
                 const float* __restrict__ tt, const __bf16* __restrict__ clsb,
                 const unsigned char* __restrict__ selbit,
                 const float* __restrict__ maskadd,
                 const float* __restrict__ rwb, const float* __restrict__ rrb,
                 __bf16* __restrict__ av)
{
    __shared__ __align__(16) __bf16 Kt[64*64];       // [j][h]
    __shared__ __align__(16) __bf16 Vt[64*64];       // [d][j]  (transposed)
    __shared__ __align__(16) __bf16 Rw[128*64];      // circular window, phys = t & 127
    __shared__ __align__(16) __bf16 Ps[4*16*64];     // per-wave P [il][jl]
    __shared__ __align__(16) __bf16 poss[4*16*84];   // per-wave pos band, stride 84

    int tid = threadIdx.x;
    int i0 = blockIdx.x * 64;
    int n  = blockIdx.y;
    int b  = blockIdx.z;
    int bS = b * S_LEN;
    int n64 = n * D_HEAD;

    int lane = tid & 63, w = tid >> 6;
    int grp = lane >> 4, lcol = lane & 15;

    // ---- Q fragments ----
    bf8 qwA[2], qrA[2];
    {
        size_t qrow = (size_t)(bS + i0 + w*16 + lcol) * D_MODEL + n64;
        #pragma unroll
        for (int kk = 0; kk < 2; ++kk) {
            int kb = kk*32 + grp*8;
            bf8 qv = *(const bf8*)(qh + qrow + kb);
            const float* wbp = rwb + n64 + kb;
            const float* rbp = rrb + n64 + kb;
            #pragma unroll
            for (int q = 0; q < 8; ++q) {
                float f = (float)qv[q];
                qwA[kk][q] = (__bf16)(f + wbp[q] * SCALE);
                qrA[kk][q] = (__bf16)(f + rbp[q] * SCALE);
            }
        }
    }

    // ---- per-row token-type values (j-independent, hoisted) ----
    float t0r[4], t1r[4];
    #pragma unroll
    for (int reg = 0; reg < 4; ++reg) {
        int gi = i0 + w*16 + grp*4 + reg;
        const float* ttrow = tt + (((size_t)(bS + gi)) * N_HEAD + n) * 2;
        t0r[reg] = ttrow[0];
        t1r[reg] = ttrow[1];
    }

    // ---- relative-shift edge fixup value: qr_row1 . r_head[0] ----
    float fixv = 0.f;
    if (i0 == 0) {
        float qv = (float)qh[((size_t)(bS + 1)) * D_MODEL + n64 + lane] + rrb[n64 + lane] * SCALE;
        float rv = (float)rhd[n64 + lane];
        float t = qv * rv;
        #pragma unroll
        for (int m = 32; m; m >>= 1) t += __shfl_xor(t, m, 64);
        fixv = t;
    }
    bool fix = (i0 == 0 && w == 0 && lane == 15);

    float m_run[4] = {-1e30f, -1e30f, -1e30f, -1e30f};
    float l_run[4] = {0.f, 0.f, 0.f, 0.f};
    f32x4 acc[4] = {};
    const f32x4 zero4 = {0.f, 0.f, 0.f, 0.f};

    for (int jt = 0; jt < 16; ++jt) {
        int j0 = jt * 64;
        int w0 = j0 - i0 + 961;            // window base t; t = w0 + logical row
        __syncthreads();

        // ---- stage K tile ----
        #pragma unroll
        for (int rep = 0; rep < 2; ++rep) {
            int idx = rep*256 + tid;
            int row = idx >> 3;
            int c8  = (idx & 7) * 8;
            bf8 v = *(const bf8*)(kh + (size_t)(bS + j0 + row) * D_MODEL + n64 + c8);
            *(bf8*)((char*)Kt + swz_addr(row, c8*2)) = v;
        }
        // ---- stage V transposed ----
        #pragma unroll
        for (int rep = 0; rep < 2; ++rep) {
            int idx = rep*256 + tid;
            int row = idx >> 3;               // j
            int c8  = (idx & 7) * 8;          // d base
            bf8 v = *(const bf8*)(vh + (size_t)(bS + j0 + row) * D_MODEL + n64 + c8);
            #pragma unroll
            for (int q = 0; q < 8; ++q) {
                int d = c8 + q;
                *((__bf16*)((char*)Vt + swz_addr(d, row*2))) = v[q];
            }
        }
        // ---- stage r_head window (rolling: 128 rows at jt=0, 64 new after) ----
        if (jt == 0) {
            #pragma unroll
            for (int rep = 0; rep < 4; ++rep) {
                int idx = rep*256 + tid;
                int rowl = idx >> 3;
                int c8  = (idx & 7) * 8;
                int t = w0 + rowl;
                bf8 v = {};
                if (t < T_LEN)
                    v = *(const bf8*)(rhd + (size_t)t * D_MODEL + n64 + c8);
                *(bf8*)((char*)Rw + swz_addr(t & 127, c8*2)) = v;
            }
        } else {
            #pragma unroll
            for (int rep = 0; rep < 2; ++rep) {
                int idx = rep*256 + tid;
                int rowl = idx >> 3;
                int c8  = (idx & 7) * 8;
                int t = w0 + 64 + rowl;
                bf8 v = {};
                if (t < T_LEN)
                    v = *(const bf8*)(rhd + (size_t)t * D_MODEL + n64 + c8);
                *(bf8*)((char*)Rw + swz_addr(t & 127, c8*2)) = v;
            }
        }
        __syncthreads();

        // ---- content scores ----
        f32x4 sc_[4] = {zero4, zero4, zero4, zero4};
        #pragma unroll
        for (int c = 0; c < 4; ++c) {
            #pragma unroll
            for (int kk = 0; kk < 2; ++kk) {
                bf8 kb = *(const bf8*)((const char*)Kt + swz_addr(c*16 + lcol, kk*64 + grp*16));
                sc_[c] = __builtin_amdgcn_mfma_f32_16x16x32_bf16(qwA[kk], kb, sc_[c], 0, 0, 0);
            }
        }
        // ---- positional: 5 window tiles ----
        int a0 = 3 - w;
        f32x4 pacc[5] = {zero4, zero4, zero4, zero4, zero4};
        #pragma unroll
        for (int pa = 0; pa < 5; ++pa) {
            #pragma unroll
            for (int kk = 0; kk < 2; ++kk) {
                int tr = w0 + (a0 + pa) * 16 + lcol;       // global t of this row
                bf8 rb = *(const bf8*)((const char*)Rw + swz_addr(tr & 127, kk*64 + grp*16));
                pacc[pa] = __builtin_amdgcn_mfma_f32_16x16x32_bf16(qrA[kk], rb, pacc[pa], 0, 0, 0);
            }
        }
        __bf16* pw = poss + w * 16 * 84;
        #pragma unroll
        for (int pa = 0; pa < 5; ++pa) {
            #pragma unroll
            for (int reg = 0; reg < 4; ++reg)
                pw[(grp*4 + reg) * 84 + pa*16 + lcol] = (__bf16)pacc[pa][reg];
        }
        asm volatile("s_waitcnt lgkmcnt(0)" ::: "memory");
        __builtin_amdgcn_sched_barrier(0);

        // ---- assemble scores: s = content + cls*(pos + ttv) + maskadd ----
        float sv[4][4];
        #pragma unroll
        for (int c = 0; c < 4; ++c) {
            int jl = c*16 + lcol;
            int gj = j0 + jl;
            float ma = maskadd[b * S_LEN + gj];
            #pragma unroll
            for (int reg = 0; reg < 4; ++reg) {
                int il = grp*4 + reg;
                int gi = i0 + w*16 + il;
                int rr = jl - il + 15;
                float pv = (float)pw[il * 84 + rr];
                if (fix && jt == 15 && c == 3 && reg == 0) pv = fixv;
                float clv = (float)clsb[(size_t)gi * S_LEN + gj];
                float ttv = selbit[((size_t)(bS + gi)) * S_LEN + gj] ? t1r[reg] : t0r[reg];
                sv[c][reg] = sc_[c][reg] + clv * (pv + ttv) + ma;
            }
        }

        // ---- online softmax ----
        float mx[4], alpha[4], rs[4];
        #pragma unroll
        for (int reg = 0; reg < 4; ++reg)
            mx[reg] = fmaxf(fmaxf(sv[0][reg], sv[1][reg]), fmaxf(sv[2][reg], sv[3][reg]));
        #pragma unroll
        for (int msk = 1; msk < 16; msk <<= 1) {
            #pragma unroll
            for (int reg = 0; reg < 4; ++reg)
                mx[reg] = fmaxf(mx[reg], __shfl_xor(mx[reg], msk, 64));
        }
        #pragma unroll
        for (int reg = 0; reg < 4; ++reg) {
            float mn = fmaxf(m_run[reg], mx[reg]);
            alpha[reg] = __expf(m_run[reg] - mn);
            m_run[reg] = mn;
            rs[reg] = 0.f;
        }
        __bf16* psw = Ps;
        #pragma unroll
        for (int c = 0; c < 4; ++c) {
            int jl = c*16 + lcol;
            #pragma unroll
            for (int reg = 0; reg < 4; ++reg) {
                int il = grp*4 + reg;
                float p = __expf(sv[c][reg] - m_run[reg]);
                rs[reg] += p;
                *((__bf16*)((char*)psw + w*2048 + swz_addr(il, jl*2))) = (__bf16)p;
            }
        }
        #pragma unroll
        for (int msk = 1; msk < 16; msk <<= 1) {
            #pragma unroll
            for (int reg = 0; reg < 4; ++reg)
                rs[reg] += __shfl_xor(rs[reg], msk, 64);
        }
        #pragma unroll
        for (int reg = 0; reg < 4; ++reg)
            l_run[reg] = l_run[reg] * alpha[reg] + rs[reg];
        #pragma unroll
        for (int c = 0; c < 4; ++c) {
            #pragma unroll
            for (int reg = 0; reg < 4; ++reg) acc[c][reg] *= alpha[reg];
        }
        asm volatile("s_waitcnt lgkmcnt(0)" ::: "memory");
        __builtin_amdgcn_sched_barrier(0);

        // ---- PV ----
        bf8 pA[2];
        #pragma unroll
        for (int kk = 0; kk < 2; ++kk)
            pA[kk] = *(const bf8*)((const char*)psw + w*2048 + swz_addr(lcol, kk*64 + grp*16));
        #pragma unroll
        for (int c = 0; c < 4; ++c) {
            #pragma unroll
            for (int kk = 0; kk < 2; ++kk) {
                bf8 vb = *(const bf8*)((const char*)Vt + swz_addr(c*16 + lcol, kk*64 + grp*16));
                acc[c] = __builtin_amdgcn_mfma_f32_16x16x32_bf16(pA[kk], vb, acc[c], 0, 0, 0);
            }
        }
    }

    // ---- epilogue (bf16 out) ----
    float inv[4];
    #pragma unroll
    for (int reg = 0; reg < 4; ++reg) inv[reg] = 1.f / l_run[reg];
    #pragma unroll
    for (int c = 0; c < 4; ++c) {
        #pragma unroll
        for (int reg = 0; reg < 4; ++reg) {
            size_t o = ((size_t)(bS + i0 + w*16 + grp*4 + reg)) * D_MODEL + n64 + c*16 + lcol;
            av[o] = (__bf16)(acc[c][reg] * inv[reg]);
        }
    }
}

// ---------------------------------------------------------------------------
// LayerNorm(query + attn_out) * g + b
// ---------------------------------------------------------------------------
__global__ __launch_bounds__(256)
void ln_kernel(const float* __restrict__ query, const float* __restrict__ ao,
               const float* __restrict__ gam, const float* __restrict__ bet,
               float* __restrict__ out)
{
    int row = blockIdx.x;
    int tid = threadIdx.x;
    size_t base = (size_t)row * D_MODEL;
    float xv[3];
    float s = 0.f, sq = 0.f;
    #pragma unroll
    for (int k = 0; k < 3; ++k) {
        int c = tid + k * 256;
        float v = query[base + c] + ao[base + c];
        xv[k] = v; s += v; sq += v * v;
    }
    for (int off = 32; off > 0; off >>= 1) {
        s  += __shfl_down(s, off);
        sq += __shfl_down(sq, off);
    }
    __shared__ float rs[4], rq[4];
    __shared__ float mean_s, inv_s;
    int wid = tid >> 6, lane = tid & 63;
    if (lane == 0) { rs[wid] = s; rq[wid] = sq; }
    __syncthreads();
    if (tid == 0) {
        float S0 = rs[0] + rs[1] + rs[2] + rs[3];
        float Q0 = rq[0] + rq[1] + rq[2] + rq[3];
        float mean = S0 / (float)D_MODEL;
        float var  = Q0 / (float)D_MODEL - mean * mean;
        mean_s = mean;
        inv_s  = rsqrtf(var + LN_EPSF);
    }
    __syncthreads();
    float mean = mean_s, inv = inv_s;
    #pragma unroll
    for (int k = 0; k < 3; ++k) {
        int c = tid + k * 256;
        out[base + c] = (xv[k] - mean) * inv * gam[c] + bet[c];
    }
}

// ---------------------------------------------------------------------------
extern "C" void kernel_launch(void* const* d_in, const int* in_sizes, int n_in,
                              void* d_out, int out_size, void* d_ws, size_t ws_size,
                              hipStream_t stream)
{
    const float* query = (const float*)d_in[0];
    const float* key   = (const float*)d_in[1];
    const float* value = (const float*)d_in[2];
    const float* r     = (const float*)d_in[3];
    const void*  ttm   = d_in[4];
    const int*   amask = (const int*)d_in[5];
    const float* cls   = (const float*)d_in[6];
    const float* Wq    = (const float*)d_in[7];
    const float* Wk    = (const float*)d_in[8];
    const float* bk    = (const float*)d_in[9];
    const float* Wv    = (const float*)d_in[10];
    const float* bv    = (const float*)d_in[11];
    const float* Wpost = (const float*)d_in[12];
    const float* bpost = (const float*)d_in[13];
    const float* ln_g  = (const float*)d_in[14];
    const float* ln_b  = (const float*)d_in[15];
    const float* rwb   = (const float*)d_in[16];
    const float* rrb   = (const float*)d_in[17];
    const float* rker  = (const float*)d_in[18];
    const float* rsb   = (const float*)d_in[19];
    const float* seg   = (const float*)d_in[20];

    char* wsb = (char*)d_ws;
    __bf16* qh  = (__bf16*)(wsb);                    //  6,291,456
    __bf16* kh  = (__bf16*)(wsb + 6291456);          //  6,291,456
    __bf16* vh  = (__bf16*)(wsb + 12582912);         //  6,291,456
    __bf16* rhd = (__bf16*)(wsb + 18874368);         //  3,145,728 (incl pad)
    float*  tt  = (float*) (wsb + 22020096);         //    393,216
    __bf16* av  = (__bf16*)(wsb + 22413312);         //  6,291,456
    float*  ao  = (float*) (wsb + 28704768);         // 12,582,912
    // selbit/clsb/maskadd overlap the ao region (written before attn,
    // consumed by attn; ao only written by post_gemm after attn completes)
    unsigned char* selbit = (unsigned char*)(wsb + 28704768);          // 4,194,304
    __bf16* clsb    = (__bf16*)(wsb + 28704768 + 4194304);             // 2,097,152
    float*  maskadd = (float*) (wsb + 28704768 + 6291456);             //    16,384
    __bf16* Wqt = (__bf16*)(wsb + 41287680);         //  1,179,648
    __bf16* Wkt = (__bf16*)(wsb + 42467328);
    __bf16* Wvt = (__bf16*)(wsb + 43646976);
    __bf16* Wpt = (__bf16*)(wsb + 44826624);
    __bf16* rkt = (__bf16*)(wsb + 46006272);
    int*    flag = (int*)  (wsb + 47185920);

    detect_kernel<<<1, 64, 0, stream>>>((const unsigned char*)ttm, flag);
    prep_sel<<<2048, 256, 0, stream>>>(ttm, flag, selbit);
    clsb_prep<<<512, 256, 0, stream>>>(cls, amask, clsb, maskadd);

    dim3 gtr(12, 12, 5);
    wtrans_kernel<<<gtr, 256, 0, stream>>>(Wq, Wk, Wv, Wpost, rker,
                                           Wqt, Wkt, Wvt, Wpt, rkt);

    dim3 gproj(6, 32, 4);
    proj_gemm<<<gproj, 256, 0, stream>>>(query, key, value, r,
                                         Wqt, Wkt, Wvt, rkt, bk, bv,
                                         qh, kh, vh, rhd);

    ttbias_kernel<<<384, 256, 0, stream>>>(qh, rsb, seg, tt);

    dim3 gattn(16, 12, 4);
    attn_kernel<<<gattn, 256, 0, stream>>>(qh, kh, vh, rhd, tt, clsb, selbit,
                                           maskadd, rwb, rrb, av);

    dim3 gpost(6, 32);
    post_gemm<<<gpost, 256, 0, stream>>>(av, Wpt, bpost, ao);

    ln_kernel<<<4096, 256, 0, stream>>>(query, ao, ln_g, ln_b, (float*)d_out);
}